// Round 7
// baseline (201.453 us; speedup 1.0000x reference)
//
#include <hip/hip_runtime.h>
#include <hip/hip_bf16.h>
#include <math.h>

#define Bc 2
#define Sc 2048
#define Dc 1024
#define Hc 16
#define HDc 64
#define Mc (Bc*Sc)   // 4096 rows

using f32x4  = __attribute__((ext_vector_type(4))) float;
using bf16x8 = __attribute__((ext_vector_type(8))) short;
using s16x4  = __attribute__((ext_vector_type(4))) short;
using uint4v = __attribute__((ext_vector_type(4))) unsigned int;

#define GAS(p) ((const __attribute__((address_space(1))) void*)(p))
#define LAS(p) ((__attribute__((address_space(3))) void*)(p))

#define QSC 0.18033688011112042f  // (1/sqrt(64)) * log2(e)

__device__ __forceinline__ short f2b(float f) {
  union { float f; unsigned u; } v; v.f = f;
  unsigned r = (v.u + 0x7fffu + ((v.u >> 16) & 1u)) >> 16;
  return (short)r;
}

// ---------------- all f32 -> bf16 converts in ONE launch ----------------
__global__ __launch_bounds__(256) void cvt_all(
    const float* __restrict__ x,
    const float* __restrict__ Wq, const float* __restrict__ Wk,
    const float* __restrict__ Wv, const float* __restrict__ Wo,
    short* __restrict__ xb, short* __restrict__ wqb, short* __restrict__ wkb,
    short* __restrict__ wvb, short* __restrict__ wob) {
  int i = blockIdx.x * 256 + threadIdx.x;
  const float* in; short* out; int idx;
  if (i < (1 << 20)) {
    in = x; out = xb; idx = i;
  } else {
    int j = i - (1 << 20);
    int s = j >> 18; idx = j & 262143;
    in  = (s == 0) ? Wq  : (s == 1) ? Wk  : (s == 2) ? Wv  : Wo;
    out = (s == 0) ? wqb : (s == 1) ? wkb : (s == 2) ? wvb : wob;
  }
  float4 v = reinterpret_cast<const float4*>(in)[idx];
  s16x4 o;
  o.x = f2b(v.x); o.y = f2b(v.y); o.z = f2b(v.z); o.w = f2b(v.w);
  reinterpret_cast<s16x4*>(out)[idx] = o;
}

// ---------------- shared 128x128x(K=1024) bf16 GEMM core, C = A * Bt^T ----------------
__device__ __forceinline__ void gemm_core_128(
    const short* __restrict__ A, const short* __restrict__ Bt,
    int m0, int n0, short* As, short* Bs, f32x4 (&acc)[4][4]) {
  const int tid = threadIdx.x;
  const int l = tid & 63;
  const int w = tid >> 6;
  const int wr = w >> 1, wc = w & 1;
  const int g = l >> 4;

  int srow[4], scol[4];
#pragma unroll
  for (int i = 0; i < 4; ++i) {
    int off = w * 1024 + i * 4096 + l * 16;
    int row = off >> 7;
    srow[i] = row;
    scol[i] = (off & 127) ^ ((row & 7) << 4);
  }
  const int rA = (wr * 64 + (l & 15)) * 128;
  const int rB = (wc * 64 + (l & 15)) * 128;
  const int sw = (l & 7) << 4;

  for (int kt = 0; kt < 16; ++kt) {
#pragma unroll
    for (int i = 0; i < 4; ++i) {
      const char* ga = (const char*)A + (size_t)(m0 + srow[i]) * 2048 + kt * 128 + scol[i];
      const char* gb = (const char*)Bt + (size_t)(n0 + srow[i]) * 2048 + kt * 128 + scol[i];
      __builtin_amdgcn_global_load_lds(GAS(ga), LAS((char*)As + w * 1024 + i * 4096), 16, 0, 0);
      __builtin_amdgcn_global_load_lds(GAS(gb), LAS((char*)Bs + w * 1024 + i * 4096), 16, 0, 0);
    }
    __syncthreads();
#pragma unroll
    for (int ks = 0; ks < 2; ++ks) {
      bf16x8 af[4], bfr[4];
#pragma unroll
      for (int mi = 0; mi < 4; ++mi)
        af[mi] = *(const bf16x8*)((const char*)As + rA + mi * 2048 + ((g * 16 + ks * 64) ^ sw));
#pragma unroll
      for (int ni = 0; ni < 4; ++ni)
        bfr[ni] = *(const bf16x8*)((const char*)Bs + rB + ni * 2048 + ((g * 16 + ks * 64) ^ sw));
#pragma unroll
      for (int mi = 0; mi < 4; ++mi)
#pragma unroll
        for (int ni = 0; ni < 4; ++ni)
          acc[mi][ni] = __builtin_amdgcn_mfma_f32_16x16x32_bf16(af[mi], bfr[ni], acc[mi][ni], 0, 0, 0);
    }
    __syncthreads();
  }
}

// ---------------- fused QKV projection (Q pre-scaled; V written transposed) ----------------
__global__ __launch_bounds__(256) void qkv_kernel(
    const short* __restrict__ xb, const short* __restrict__ wq,
    const short* __restrict__ wk, const short* __restrict__ wv,
    short* __restrict__ Qb, short* __restrict__ Kb, short* __restrict__ Vtg) {
  __shared__ short As[128 * 64];
  __shared__ short Bs[128 * 64];
  const int mt = blockIdx.x, yb = blockIdx.y;
  const int sel = yb >> 3, nb = yb & 7;
  const short* Wt = (sel == 0) ? wq : (sel == 1) ? wk : wv;
  f32x4 acc[4][4];
#pragma unroll
  for (int i = 0; i < 4; ++i)
#pragma unroll
    for (int j = 0; j < 4; ++j)
#pragma unroll
      for (int r = 0; r < 4; ++r) acc[i][j][r] = 0.0f;
  gemm_core_128(xb, Wt, mt * 128, nb * 128, As, Bs, acc);
  const int l = threadIdx.x & 63, w = threadIdx.x >> 6;
  const int wr = w >> 1, wc = w & 1, g = l >> 4, c = l & 15;

  if (sel == 2) {
    // V: write directly transposed [B,H,HD,S]; 4 r-values = 4 consecutive s
#pragma unroll
    for (int mi = 0; mi < 4; ++mi)
#pragma unroll
      for (int ni = 0; ni < 4; ++ni) {
        int n = nb * 128 + wc * 64 + ni * 16 + c;
        int h = n >> 6, hd = n & 63;
        int m = mt * 128 + wr * 64 + mi * 16 + g * 4;
        int b = m >> 11, s = m & 2047;
        s16x4 pk;
#pragma unroll
        for (int r = 0; r < 4; ++r) pk[r] = f2b(acc[mi][ni][r]);
        *(s16x4*)(Vtg + ((size_t)(b * 16 + h) * 64 + hd) * 2048 + s) = pk;
      }
  } else {
    short* Ob = (sel == 0) ? Qb : Kb;
    const float oscale = (sel == 0) ? QSC : 1.0f;
#pragma unroll
    for (int mi = 0; mi < 4; ++mi)
#pragma unroll
      for (int ni = 0; ni < 4; ++ni) {
        int n = nb * 128 + wc * 64 + ni * 16 + c;
        int h = n >> 6, hd = n & 63;
#pragma unroll
        for (int r = 0; r < 4; ++r) {
          int m = mt * 128 + wr * 64 + mi * 16 + g * 4 + r;
          int b = m >> 11, s = m & 2047;
          Ob[((size_t)(b * 16 + h) * 2048 + s) * 64 + hd] = f2b(acc[mi][ni][r] * oscale);
        }
      }
  }
}

// ---------------- output projection + bias ----------------
__global__ __launch_bounds__(256) void oproj_kernel(
    const short* __restrict__ ab, const short* __restrict__ wo,
    const float* __restrict__ bo, float* __restrict__ out) {
  __shared__ short As[128 * 64];
  __shared__ short Bs[128 * 64];
  const int mt = blockIdx.x, nb = blockIdx.y;
  f32x4 acc[4][4];
#pragma unroll
  for (int i = 0; i < 4; ++i)
#pragma unroll
    for (int j = 0; j < 4; ++j)
#pragma unroll
      for (int r = 0; r < 4; ++r) acc[i][j][r] = 0.0f;
  gemm_core_128(ab, wo, mt * 128, nb * 128, As, Bs, acc);
  const int l = threadIdx.x & 63, w = threadIdx.x >> 6;
  const int wr = w >> 1, wc = w & 1, g = l >> 4;
#pragma unroll
  for (int mi = 0; mi < 4; ++mi)
#pragma unroll
    for (int ni = 0; ni < 4; ++ni) {
      int n = nb * 128 + wc * 64 + ni * 16 + (l & 15);
      float bias = bo[n];
#pragma unroll
      for (int r = 0; r < 4; ++r) {
        int m = mt * 128 + wr * 64 + mi * 16 + g * 4 + r;
        out[(size_t)m * 1024 + n] = acc[mi][ni][r] + bias;
      }
    }
}

// ---------------- flash attention v6: 64-row q-blocks for occupancy ----------------
// Same verified skeleton as v4 (triple-buffer, 1 barrier/tile, vmcnt(2),
// swapped QK^T, permlane P-routing, no-max softmax). Each block now covers
// 64 q-rows; wave = (qg: 16 q-rows) x (h: kv-half). Grid 1024 blocks,
// 48KB LDS -> 3 blocks/CU = 6 waves/SIMD (was grid-limited at 4).
__global__ __launch_bounds__(512, 6) void attn_kernel(
    const short* __restrict__ Qb, const short* __restrict__ Kb,
    const short* __restrict__ Vtg, short* __restrict__ ab) {
  __shared__ char lds[49152];   // K bufs @0/8K/16K, V bufs @24K/32K/40K
  const int bh = blockIdx.x;
  const int qt = blockIdx.y;
  const int tid = threadIdx.x, l = tid & 63, w = tid >> 6;
  const int qg = w >> 1, h = w & 1;
  const int g = l >> 4, c = l & 15;
  const int sw = (l & 7) << 4;
  const bool godd = (l & 16) != 0;
  const short* Qp = Qb + (size_t)bh * Sc * HDc;
  const char* KpB = (const char*)(Kb + (size_t)bh * Sc * HDc);
  const char* VtB = (const char*)(Vtg + (size_t)bh * Sc * HDc);
  const int q0 = qt * 64 + qg * 16;

  // Q b-frag: lane holds Q[q0+c][hd = ks*32 + g*8 .. +8] (pre-scaled)
  bf16x8 bq[2];
#pragma unroll
  for (int ks = 0; ks < 2; ++ks)
    bq[ks] = *(const bf16x8*)(Qp + (size_t)(q0 + c) * 64 + ks * 32 + g * 8);

  f32x4 o[4];
  float lsum = 0.0f;
#pragma unroll
  for (int ohf = 0; ohf < 4; ++ohf)
#pragma unroll
    for (int r = 0; r < 4; ++r) o[ohf][r] = 0.0f;

  // staging: 16 x 1KB loads per tile, 1 K-load + 1 V-load per wave
  const int soff = w * 1024 + l * 16;
  const int srow = soff >> 7;
  const int scol = (soff & 127) ^ ((srow & 7) << 4);
  const size_t koff = (size_t)srow * 128 + scol;    // K tile local
  const size_t voff = (size_t)srow * 4096 + scol;   // V global (row stride S*2)
  const int ldst = w * 1024;                        // wave-uniform LDS base

#define ISSUE3(t_) do {                                                               \
    char* kd_ = lds + ((t_) % 3) * 8192 + ldst;                                       \
    char* vd_ = lds + 24576 + ((t_) % 3) * 8192 + ldst;                               \
    __builtin_amdgcn_global_load_lds(GAS(KpB + (size_t)(t_) * 8192 + koff), LAS(kd_), 16, 0, 0); \
    __builtin_amdgcn_global_load_lds(GAS(VtB + (size_t)(t_) * 128  + voff), LAS(vd_), 16, 0, 0); \
  } while (0)

  ISSUE3(0);
  ISSUE3(1);

  for (int t = 0; t < 32; ++t) {
    if (t < 31) {
      asm volatile("s_waitcnt vmcnt(2)" ::: "memory");
    } else {
      asm volatile("s_waitcnt vmcnt(0)" ::: "memory");
    }
    __builtin_amdgcn_s_barrier();
    if (t < 30) ISSUE3(t + 2);

    const char* KsB = lds + (t % 3) * 8192;
    const char* VsB = lds + 24576 + (t % 3) * 8192;

    // QK^T (kv rows 32h..32h+31): s[kf2], kv = 16*(2h+kf2) + 4g + r, q = c
    f32x4 s[2];
#pragma unroll
    for (int kf2 = 0; kf2 < 2; ++kf2)
#pragma unroll
      for (int r = 0; r < 4; ++r) s[kf2][r] = 0.0f;
#pragma unroll
    for (int ks = 0; ks < 2; ++ks) {
      bf16x8 ak[2];
#pragma unroll
      for (int kf2 = 0; kf2 < 2; ++kf2) {
        int row = (2 * h + kf2) * 16 + c;
        ak[kf2] = *(const bf16x8*)(KsB + row * 128 + ((ks * 64 + g * 16) ^ sw));
      }
      __builtin_amdgcn_s_setprio(1);
#pragma unroll
      for (int kf2 = 0; kf2 < 2; ++kf2)
        s[kf2] = __builtin_amdgcn_mfma_f32_16x16x32_bf16(ak[kf2], bq[ks], s[kf2], 0, 0, 0);
      __builtin_amdgcn_s_setprio(0);
    }

    // softmax-lite + pack + route (contraction slice ks2 = h implicit)
    bf16x8 pb;
    {
      float p[2][4];
#pragma unroll
      for (int kf2 = 0; kf2 < 2; ++kf2)
#pragma unroll
        for (int r = 0; r < 4; ++r)
          p[kf2][r] = __builtin_amdgcn_exp2f(s[kf2][r]);
      float t0 = (p[0][0] + p[0][1]) + (p[0][2] + p[0][3]);
      float t1 = (p[1][0] + p[1][1]) + (p[1][2] + p[1][3]);
      lsum += t0 + t1;

      unsigned dw[2][2];
#pragma unroll
      for (int kf2 = 0; kf2 < 2; ++kf2)
#pragma unroll
        for (int d = 0; d < 2; ++d)
          asm("v_cvt_pk_bf16_f32 %0, %1, %2" : "=v"(dw[kf2][d]) : "v"(p[kf2][2 * d]), "v"(p[kf2][2 * d + 1]));

      unsigned T[4];
#pragma unroll
      for (int d = 0; d < 2; ++d) {
        unsigned Av = dw[0][d], Bv = dw[1][d];
        asm("v_permlane32_swap_b32 %0, %1" : "+v"(Av), "+v"(Bv));
        unsigned sAv = (unsigned)__shfl_xor((int)Av, 16);
        unsigned sBv = (unsigned)__shfl_xor((int)Bv, 16);
        T[d]     = godd ? sBv : Av;
        T[d + 2] = godd ? Bv  : sAv;
      }
      uint4v t4; t4.x = T[0]; t4.y = T[1]; t4.z = T[2]; t4.w = T[3];
      pb = __builtin_bit_cast(bf16x8, t4);
    }

    // PV (contraction slice ks2 = h): o[ohf] += mfma(V_frag, P^T_frag)
    {
      bf16x8 av[4];
#pragma unroll
      for (int ohf = 0; ohf < 4; ++ohf) {
        int row = ohf * 16 + c;
        av[ohf] = *(const bf16x8*)(VsB + row * 128 + ((h * 64 + g * 16) ^ sw));
      }
      __builtin_amdgcn_s_setprio(1);
#pragma unroll
      for (int ohf = 0; ohf < 4; ++ohf)
        o[ohf] = __builtin_amdgcn_mfma_f32_16x16x32_bf16(av[ohf], pb, o[ohf], 0, 0, 0);
      __builtin_amdgcn_s_setprio(0);
    }
  }

  // ---- wave-pair merge + output ----
  // So: 16KB @ lds[0..16K] (K bufs 0/1), XOR-swizzled; Sl: 1KB @ lds[24K]
  float* Sl = (float*)(lds + 24576);
  const int b = bh >> 4, hh = bh & 15;

  __syncthreads();
  if (h == 1) {
#pragma unroll
    for (int ohf = 0; ohf < 4; ++ohf)
      *(f32x4*)(lds + qg * 4096 + ((l * 64 + ohf * 16) ^ ((l & 7) << 4))) = o[ohf];
    Sl[qg * 64 + l] = lsum;
  }
  __syncthreads();
  if (h == 0) {
    float lt = lsum + Sl[qg * 64 + l];
    lt += __shfl_xor(lt, 16);
    lt += __shfl_xor(lt, 32);
    float inv = 1.0f / lt;
    int q = q0 + c;
    short* dst = ab + (size_t)(b * Sc + q) * Dc + hh * 64 + g * 4;
#pragma unroll
    for (int ohf = 0; ohf < 4; ++ohf) {
      f32x4 om = o[ohf] +
          *(const f32x4*)(lds + qg * 4096 + ((l * 64 + ohf * 16) ^ ((l & 7) << 4)));
      s16x4 pk4;
#pragma unroll
      for (int r = 0; r < 4; ++r) pk4[r] = f2b(om[r] * inv);
      *(s16x4*)(dst + ohf * 16) = pk4;
    }
  }
}

// ---------------- launch ----------------
extern "C" void kernel_launch(void* const* d_in, const int* in_sizes, int n_in,
                              void* d_out, int out_size, void* d_ws, size_t ws_size,
                              hipStream_t stream) {
  const float* x  = (const float*)d_in[0];
  const float* Wq = (const float*)d_in[1];
  const float* Wk = (const float*)d_in[2];
  const float* Wv = (const float*)d_in[3];
  const float* Wo = (const float*)d_in[4];
  const float* bo = (const float*)d_in[5];
  float* out = (float*)d_out;

  char* p = (char*)d_ws;
  short* xb    = (short*)p; p += (size_t)Mc * Dc * 2;   // 8 MB
  short* wqb   = (short*)p; p += (size_t)Dc * Dc * 2;   // 2 MB
  short* wkb   = (short*)p; p += (size_t)Dc * Dc * 2;
  short* wvb   = (short*)p; p += (size_t)Dc * Dc * 2;
  short* wob   = (short*)p; p += (size_t)Dc * Dc * 2;
  short* Qb    = (short*)p; p += (size_t)Mc * Dc * 2;   // [B,H,S,HD], Q pre-scaled
  short* Kb    = (short*)p; p += (size_t)Mc * Dc * 2;   // [B,H,S,HD]
  short* Vtg   = (short*)p; p += (size_t)Mc * Dc * 2;   // [B,H,HD,S] (written by qkv)
  short* attnb = (short*)p; p += (size_t)Mc * Dc * 2;

  cvt_all<<<8192, 256, 0, stream>>>(x, Wq, Wk, Wv, Wo, xb, wqb, wkb, wvb, wob);
  qkv_kernel<<<dim3(Mc / 128, 24), 256, 0, stream>>>(xb, wqb, wkb, wvb, Qb, Kb, Vtg);
  attn_kernel<<<dim3(Bc * Hc, Sc / 64), 512, 0, stream>>>(Qb, Kb, Vtg, attnb);
  oproj_kernel<<<dim3(Mc / 128, Dc / 128), 256, 0, stream>>>(attnb, wob, bo, out);
}

// Round 9
// 187.224 us; speedup vs baseline: 1.0760x; 1.0760x over previous
//
#include <hip/hip_runtime.h>
#include <hip/hip_bf16.h>
#include <math.h>

#define Bc 2
#define Sc 2048
#define Dc 1024
#define Hc 16
#define HDc 64
#define Mc (Bc*Sc)   // 4096 rows

using f32x4  = __attribute__((ext_vector_type(4))) float;
using bf16x8 = __attribute__((ext_vector_type(8))) short;
using s16x4  = __attribute__((ext_vector_type(4))) short;
using uint4v = __attribute__((ext_vector_type(4))) unsigned int;

#define GAS(p) ((const __attribute__((address_space(1))) void*)(p))
#define LAS(p) ((__attribute__((address_space(3))) void*)(p))

#define QSC 0.18033688011112042f  // (1/sqrt(64)) * log2(e)

#define SCB __builtin_amdgcn_sched_barrier(0)
#define BARR __builtin_amdgcn_s_barrier()

__device__ __forceinline__ short f2b(float f) {
  union { float f; unsigned u; } v; v.f = f;
  unsigned r = (v.u + 0x7fffu + ((v.u >> 16) & 1u)) >> 16;
  return (short)r;
}

// ---------------- all f32 -> bf16 converts in ONE launch ----------------
__global__ __launch_bounds__(256) void cvt_all(
    const float* __restrict__ x,
    const float* __restrict__ Wq, const float* __restrict__ Wk,
    const float* __restrict__ Wv, const float* __restrict__ Wo,
    short* __restrict__ xb, short* __restrict__ wqb, short* __restrict__ wkb,
    short* __restrict__ wvb, short* __restrict__ wob) {
  int i = blockIdx.x * 256 + threadIdx.x;
  const float* in; short* out; int idx;
  if (i < (1 << 20)) {
    in = x; out = xb; idx = i;
  } else {
    int j = i - (1 << 20);
    int s = j >> 18; idx = j & 262143;
    in  = (s == 0) ? Wq  : (s == 1) ? Wk  : (s == 2) ? Wv  : Wo;
    out = (s == 0) ? wqb : (s == 1) ? wkb : (s == 2) ? wvb : wob;
  }
  float4 v = reinterpret_cast<const float4*>(in)[idx];
  s16x4 o;
  o.x = f2b(v.x); o.y = f2b(v.y); o.z = f2b(v.z); o.w = f2b(v.w);
  reinterpret_cast<s16x4*>(out)[idx] = o;
}

// ---------------- 128x128 bf16 GEMM core (verified; used by oproj) ----------------
__device__ __forceinline__ void gemm_core_128(
    const short* __restrict__ A, const short* __restrict__ Bt,
    int m0, int n0, short* As, short* Bs, f32x4 (&acc)[4][4]) {
  const int tid = threadIdx.x;
  const int l = tid & 63;
  const int w = tid >> 6;
  const int wr = w >> 1, wc = w & 1;
  const int g = l >> 4;

  int srow[4], scol[4];
#pragma unroll
  for (int i = 0; i < 4; ++i) {
    int off = w * 1024 + i * 4096 + l * 16;
    int row = off >> 7;
    srow[i] = row;
    scol[i] = (off & 127) ^ ((row & 7) << 4);
  }
  const int rA = (wr * 64 + (l & 15)) * 128;
  const int rB = (wc * 64 + (l & 15)) * 128;
  const int sw = (l & 7) << 4;

  for (int kt = 0; kt < 16; ++kt) {
#pragma unroll
    for (int i = 0; i < 4; ++i) {
      const char* ga = (const char*)A + (size_t)(m0 + srow[i]) * 2048 + kt * 128 + scol[i];
      const char* gb = (const char*)Bt + (size_t)(n0 + srow[i]) * 2048 + kt * 128 + scol[i];
      __builtin_amdgcn_global_load_lds(GAS(ga), LAS((char*)As + w * 1024 + i * 4096), 16, 0, 0);
      __builtin_amdgcn_global_load_lds(GAS(gb), LAS((char*)Bs + w * 1024 + i * 4096), 16, 0, 0);
    }
    __syncthreads();
#pragma unroll
    for (int ks = 0; ks < 2; ++ks) {
      bf16x8 af[4], bfr[4];
#pragma unroll
      for (int mi = 0; mi < 4; ++mi)
        af[mi] = *(const bf16x8*)((const char*)As + rA + mi * 2048 + ((g * 16 + ks * 64) ^ sw));
#pragma unroll
      for (int ni = 0; ni < 4; ++ni)
        bfr[ni] = *(const bf16x8*)((const char*)Bs + rB + ni * 2048 + ((g * 16 + ks * 64) ^ sw));
#pragma unroll
      for (int mi = 0; mi < 4; ++mi)
#pragma unroll
        for (int ni = 0; ni < 4; ++ni)
          acc[mi][ni] = __builtin_amdgcn_mfma_f32_16x16x32_bf16(af[mi], bfr[ni], acc[mi][ni], 0, 0, 0);
    }
    __syncthreads();
  }
}

// ---------------- QKV: 256x256 8-phase GEMM (T2+T3+T4+T5) ----------------
// 512 thr = 8 waves (2M x 4N); per-wave C = 128x64; BK=64; LDS 128KB dbuf.
// Per-wave-tailored staging: wave stages only its A-half + B-quarter.
// Stream order per K-tile [Alo,Alo,Blo,Blo,Bhi,Bhi,Ahi,Ahi] => steady-state
// counted wait vmcnt(4) at ends of phases 1,2,4 (none at 3); tail 2/0.
// sched_barrier(0) after every s_barrier pins phase compartments (rule #18).
__global__ __launch_bounds__(512, 2) void qkv_kernel(
    const short* __restrict__ xb, const short* __restrict__ wq,
    const short* __restrict__ wk, const short* __restrict__ wv,
    short* __restrict__ Qb, short* __restrict__ Kb, short* __restrict__ Vtg) {
  __shared__ char lds[131072];   // A: [db][half] 4x16KB @0; B: [db][quarter] @64K
  const int tid = threadIdx.x, l = tid & 63, w = tid >> 6;
  const int g = l >> 4, c = l & 15;
  const int sw = (l & 7) << 4;
  const int wm = w >> 2, wn = w & 3;
  const int mt = blockIdx.x, nb = blockIdx.y;
  const int sel = nb >> 2, nbq = nb & 3;
  const short* Wt = (sel == 0) ? wq : (sel == 1) ? wk : wv;
  const char* Ag = (const char*)xb;
  const char* Bg = (const char*)Wt;

  // staging geometry
  const int la = (w & 3) * 64 + l;           // A-group local id (0..255)
  const int lb = (w >> 2) * 64 + l;          // B-group local id (0..127)
  const int arow0 = la >> 3;                 // + j*32 (+ hi*64)
  const int acol  = ((la * 16) & 127) ^ ((arow0 & 7) << 4);
  const int brow0 = lb >> 3;                 // + j*16 (+ hi*32)
  const int bcol  = ((lb * 16) & 127) ^ ((brow0 & 7) << 4);

#define STG_A(t_, hi_) do {                                                           \
    char* d_ = lds + ((((t_) & 1) * 2 + wm) << 14) + (w & 3) * 1024 + (hi_) * 8192;   \
    const char* s_ = Ag + (size_t)(mt * 256 + wm * 128 + (hi_) * 64 + arow0) * 2048   \
                     + (t_) * 128 + acol;                                             \
    __builtin_amdgcn_global_load_lds(GAS(s_), LAS(d_), 16, 0, 0);                     \
    __builtin_amdgcn_global_load_lds(GAS(s_ + 32 * 2048), LAS(d_ + 4096), 16, 0, 0);  \
  } while (0)

#define STG_B(t_, hi_) do {                                                           \
    char* d_ = lds + 65536 + ((t_) & 1) * 32768 + wn * 8192 + (w >> 2) * 1024         \
               + (hi_) * 4096;                                                        \
    const char* s_ = Bg + (size_t)(nbq * 256 + wn * 64 + (hi_) * 32 + brow0) * 2048   \
                     + (t_) * 128 + bcol;                                             \
    __builtin_amdgcn_global_load_lds(GAS(s_), LAS(d_), 16, 0, 0);                     \
    __builtin_amdgcn_global_load_lds(GAS(s_ + 16 * 2048), LAS(d_ + 2048), 16, 0, 0);  \
  } while (0)

  f32x4 acc[8][4];
#pragma unroll
  for (int i = 0; i < 8; ++i)
#pragma unroll
    for (int j = 0; j < 4; ++j)
#pragma unroll
      for (int r = 0; r < 4; ++r) acc[i][j][r] = 0.0f;

  bf16x8 a[4][2], blo[2][2], bhi[2][2];

#define LD_A(mh_) do {                                                                \
    _Pragma("unroll")                                                                 \
    for (int mi2 = 0; mi2 < 4; ++mi2)                                                 \
      _Pragma("unroll")                                                               \
      for (int ks = 0; ks < 2; ++ks)                                                  \
        a[mi2][ks] = *(const bf16x8*)(Ah + ((mh_) * 64 + mi2 * 16 + c) * 128 +        \
                                      ((ks * 64 + g * 16) ^ sw));                     \
  } while (0)

#define LD_B(arr_, nh_) do {                                                          \
    _Pragma("unroll")                                                                 \
    for (int ni2 = 0; ni2 < 2; ++ni2)                                                 \
      _Pragma("unroll")                                                               \
      for (int ks = 0; ks < 2; ++ks)                                                  \
        arr_[ni2][ks] = *(const bf16x8*)(Bq + ((nh_) * 32 + ni2 * 16 + c) * 128 +     \
                                         ((ks * 64 + g * 16) ^ sw));                  \
  } while (0)

#define MMQ(mh_, arr_, nh_) do {                                                      \
    __builtin_amdgcn_s_setprio(1);                                                    \
    _Pragma("unroll")                                                                 \
    for (int ks = 0; ks < 2; ++ks)                                                    \
      _Pragma("unroll")                                                               \
      for (int mi2 = 0; mi2 < 4; ++mi2)                                               \
        _Pragma("unroll")                                                             \
        for (int ni2 = 0; ni2 < 2; ++ni2)                                             \
          acc[(mh_) * 4 + mi2][(nh_) * 2 + ni2] =                                     \
              __builtin_amdgcn_mfma_f32_16x16x32_bf16(                                \
                  a[mi2][ks], arr_[ni2][ks], acc[(mh_) * 4 + mi2][(nh_) * 2 + ni2],   \
                  0, 0, 0);                                                           \
    __builtin_amdgcn_s_setprio(0);                                                    \
  } while (0)

  // prologue: stage tile 0 fully in stream order; establish invariant
  STG_A(0, 0); STG_B(0, 0); STG_B(0, 1); STG_A(0, 1);
  asm volatile("s_waitcnt vmcnt(4)" ::: "memory");
  BARR; SCB;

  for (int t = 0; t < 16; ++t) {
    const int db = t & 1;
    const char* Ah = lds + ((db * 2 + wm) << 14);
    const char* Bq = lds + 65536 + db * 32768 + wn * 8192;
    const bool st = t < 15;

    // ---- phase 1: quadrant (0,0)
    LD_A(0); LD_B(blo, 0);
    if (st) STG_A(t + 1, 0);
    BARR; SCB;
    MMQ(0, blo, 0);
    if (st) asm volatile("s_waitcnt vmcnt(4)" ::: "memory");
    else    asm volatile("s_waitcnt vmcnt(2)" ::: "memory");
    BARR; SCB;

    // ---- phase 2: quadrant (0,1)
    LD_B(bhi, 1);
    if (st) STG_B(t + 1, 0);
    BARR; SCB;
    MMQ(0, bhi, 1);
    if (st) asm volatile("s_waitcnt vmcnt(4)" ::: "memory");
    else    asm volatile("s_waitcnt vmcnt(0)" ::: "memory");
    BARR; SCB;

    // ---- phase 3: quadrant (1,1)
    LD_A(1);
    if (st) STG_B(t + 1, 1);
    BARR; SCB;
    MMQ(1, bhi, 1);
    BARR; SCB;

    // ---- phase 4: quadrant (1,0)
    if (st) STG_A(t + 1, 1);
    BARR; SCB;
    MMQ(1, blo, 0);
    if (st) {
      asm volatile("s_waitcnt vmcnt(4)" ::: "memory");
      BARR; SCB;
    }
  }

  // ---- epilogue: Q/K row-major per-head; V written transposed [B,H,HD,S]
  if (sel == 2) {
#pragma unroll
    for (int mi = 0; mi < 8; ++mi)
#pragma unroll
      for (int ni = 0; ni < 4; ++ni) {
        int n = nbq * 256 + wn * 64 + ni * 16 + c;
        int h = n >> 6, hd = n & 63;
        int m = mt * 256 + wm * 128 + mi * 16 + g * 4;
        int b = m >> 11, s = m & 2047;
        s16x4 pk;
#pragma unroll
        for (int r = 0; r < 4; ++r) pk[r] = f2b(acc[mi][ni][r]);
        *(s16x4*)(Vtg + ((size_t)(b * 16 + h) * 64 + hd) * 2048 + s) = pk;
      }
  } else {
    short* Ob = (sel == 0) ? Qb : Kb;
    const float oscale = (sel == 0) ? QSC : 1.0f;
#pragma unroll
    for (int mi = 0; mi < 8; ++mi)
#pragma unroll
      for (int ni = 0; ni < 4; ++ni) {
        int n = nbq * 256 + wn * 64 + ni * 16 + c;
        int h = n >> 6, hd = n & 63;
#pragma unroll
        for (int r = 0; r < 4; ++r) {
          int m = mt * 256 + wm * 128 + mi * 16 + g * 4 + r;
          int b = m >> 11, s = m & 2047;
          Ob[((size_t)(b * 16 + h) * 2048 + s) * 64 + hd] = f2b(acc[mi][ni][r] * oscale);
        }
      }
  }
}

// ---------------- output projection + bias ----------------
__global__ __launch_bounds__(256) void oproj_kernel(
    const short* __restrict__ ab, const short* __restrict__ wo,
    const float* __restrict__ bo, float* __restrict__ out) {
  __shared__ short As[128 * 64];
  __shared__ short Bs[128 * 64];
  const int mt = blockIdx.x, nb = blockIdx.y;
  f32x4 acc[4][4];
#pragma unroll
  for (int i = 0; i < 4; ++i)
#pragma unroll
    for (int j = 0; j < 4; ++j)
#pragma unroll
      for (int r = 0; r < 4; ++r) acc[i][j][r] = 0.0f;
  gemm_core_128(ab, wo, mt * 128, nb * 128, As, Bs, acc);
  const int l = threadIdx.x & 63, w = threadIdx.x >> 6;
  const int wr = w >> 1, wc = w & 1, g = l >> 4;
#pragma unroll
  for (int mi = 0; mi < 4; ++mi)
#pragma unroll
    for (int ni = 0; ni < 4; ++ni) {
      int n = nb * 128 + wc * 64 + ni * 16 + (l & 15);
      float bias = bo[n];
#pragma unroll
      for (int r = 0; r < 4; ++r) {
        int m = mt * 128 + wr * 64 + mi * 16 + g * 4 + r;
        out[(size_t)m * 1024 + n] = acc[mi][ni][r] + bias;
      }
    }
}

// ---------------- flash attention v4 (round-6 verified; +epilogue swizzle) ----------------
__global__ __launch_bounds__(512, 4) void attn_kernel(
    const short* __restrict__ Qb, const short* __restrict__ Kb,
    const short* __restrict__ Vtg, short* __restrict__ ab) {
  __shared__ char lds[49152];   // K bufs @0/8K/16K, V bufs @24K/32K/40K
  const int bh = blockIdx.x;
  const int qt = blockIdx.y;
  const int tid = threadIdx.x, l = tid & 63, w = tid >> 6;
  const int qg = w >> 1, h = w & 1;
  const int g = l >> 4, c = l & 15;
  const int sw = (l & 7) << 4;
  const bool godd = (l & 16) != 0;
  const short* Qp = Qb + (size_t)bh * Sc * HDc;
  const char* KpB = (const char*)(Kb + (size_t)bh * Sc * HDc);
  const char* VtB = (const char*)(Vtg + (size_t)bh * Sc * HDc);
  const int q0 = qt * 128 + qg * 32;

  bf16x8 bq[2][2];
#pragma unroll
  for (int qf = 0; qf < 2; ++qf)
#pragma unroll
    for (int ks = 0; ks < 2; ++ks)
      bq[qf][ks] = *(const bf16x8*)(Qp + (size_t)(q0 + qf * 16 + c) * 64 + ks * 32 + g * 8);

  f32x4 o[2][4];
  float lsum[2] = {0.0f, 0.0f};
#pragma unroll
  for (int qf = 0; qf < 2; ++qf)
#pragma unroll
    for (int ohf = 0; ohf < 4; ++ohf)
#pragma unroll
      for (int r = 0; r < 4; ++r) o[qf][ohf][r] = 0.0f;

  const int soff = w * 1024 + l * 16;
  const int srow = soff >> 7;
  const int scol = (soff & 127) ^ ((srow & 7) << 4);
  const size_t koff = (size_t)srow * 128 + scol;
  const size_t voff = (size_t)srow * 4096 + scol;
  const int ldst = w * 1024;

#define ISSUE3(t_) do {                                                               \
    char* kd_ = lds + ((t_) % 3) * 8192 + ldst;                                       \
    char* vd_ = lds + 24576 + ((t_) % 3) * 8192 + ldst;                               \
    __builtin_amdgcn_global_load_lds(GAS(KpB + (size_t)(t_) * 8192 + koff), LAS(kd_), 16, 0, 0); \
    __builtin_amdgcn_global_load_lds(GAS(VtB + (size_t)(t_) * 128  + voff), LAS(vd_), 16, 0, 0); \
  } while (0)

  ISSUE3(0);
  ISSUE3(1);

  for (int t = 0; t < 32; ++t) {
    if (t < 31) {
      asm volatile("s_waitcnt vmcnt(2)" ::: "memory");
    } else {
      asm volatile("s_waitcnt vmcnt(0)" ::: "memory");
    }
    __builtin_amdgcn_s_barrier();
    if (t < 30) ISSUE3(t + 2);

    const char* KsB = lds + (t % 3) * 8192;
    const char* VsB = lds + 24576 + (t % 3) * 8192;

    f32x4 s[2][2];
#pragma unroll
    for (int qf = 0; qf < 2; ++qf)
#pragma unroll
      for (int kf2 = 0; kf2 < 2; ++kf2)
#pragma unroll
        for (int r = 0; r < 4; ++r) s[qf][kf2][r] = 0.0f;
#pragma unroll
    for (int ks = 0; ks < 2; ++ks) {
      bf16x8 ak[2];
#pragma unroll
      for (int kf2 = 0; kf2 < 2; ++kf2) {
        int row = (2 * h + kf2) * 16 + c;
        ak[kf2] = *(const bf16x8*)(KsB + row * 128 + ((ks * 64 + g * 16) ^ sw));
      }
      __builtin_amdgcn_s_setprio(1);
#pragma unroll
      for (int qf = 0; qf < 2; ++qf)
#pragma unroll
        for (int kf2 = 0; kf2 < 2; ++kf2)
          s[qf][kf2] = __builtin_amdgcn_mfma_f32_16x16x32_bf16(ak[kf2], bq[qf][ks], s[qf][kf2], 0, 0, 0);
      __builtin_amdgcn_s_setprio(0);
    }

    bf16x8 pb[2];
#pragma unroll
    for (int qf = 0; qf < 2; ++qf) {
      float p[2][4];
#pragma unroll
      for (int kf2 = 0; kf2 < 2; ++kf2)
#pragma unroll
        for (int r = 0; r < 4; ++r)
          p[kf2][r] = __builtin_amdgcn_exp2f(s[qf][kf2][r]);
      float t0 = (p[0][0] + p[0][1]) + (p[0][2] + p[0][3]);
      float t1 = (p[1][0] + p[1][1]) + (p[1][2] + p[1][3]);
      lsum[qf] += t0 + t1;

      unsigned dw[2][2];
#pragma unroll
      for (int kf2 = 0; kf2 < 2; ++kf2)
#pragma unroll
        for (int d = 0; d < 2; ++d)
          asm("v_cvt_pk_bf16_f32 %0, %1, %2" : "=v"(dw[kf2][d]) : "v"(p[kf2][2 * d]), "v"(p[kf2][2 * d + 1]));

      unsigned T[4];
#pragma unroll
      for (int d = 0; d < 2; ++d) {
        unsigned Av = dw[0][d], Bv = dw[1][d];
        asm("v_permlane32_swap_b32 %0, %1" : "+v"(Av), "+v"(Bv));
        unsigned sAv = (unsigned)__shfl_xor((int)Av, 16);
        unsigned sBv = (unsigned)__shfl_xor((int)Bv, 16);
        T[d]     = godd ? sBv : Av;
        T[d + 2] = godd ? Bv  : sAv;
      }
      uint4v t4; t4.x = T[0]; t4.y = T[1]; t4.z = T[2]; t4.w = T[3];
      pb[qf] = __builtin_bit_cast(bf16x8, t4);
    }

    {
      bf16x8 av[4];
#pragma unroll
      for (int ohf = 0; ohf < 4; ++ohf) {
        int row = ohf * 16 + c;
        av[ohf] = *(const bf16x8*)(VsB + row * 128 + ((h * 64 + g * 16) ^ sw));
      }
      __builtin_amdgcn_s_setprio(1);
#pragma unroll
      for (int ohf = 0; ohf < 4; ++ohf) {
        o[0][ohf] = __builtin_amdgcn_mfma_f32_16x16x32_bf16(av[ohf], pb[0], o[0][ohf], 0, 0, 0);
        o[1][ohf] = __builtin_amdgcn_mfma_f32_16x16x32_bf16(av[ohf], pb[1], o[1][ohf], 0, 0, 0);
      }
      __builtin_amdgcn_s_setprio(0);
    }
  }

  // ---- wave-pair merge + output (XOR-swizzled scratch) ----
  float* Sl = (float*)(lds + 24576);
  const int b = bh >> 4, hh = bh & 15;
  float lv[2];

  __syncthreads();
#pragma unroll
  for (int qf = 0; qf < 2; ++qf) {
    if (h == 1) {
#pragma unroll
      for (int ohf = 0; ohf < 4; ++ohf)
        *(f32x4*)(lds + qg * 4096 + ((l * 64 + ohf * 16) ^ ((l & 7) << 4))) = o[qf][ohf];
      if (qf == 0) {
        Sl[qg * 128 + l * 2 + 0] = lsum[0];
        Sl[qg * 128 + l * 2 + 1] = lsum[1];
      }
    }
    __syncthreads();
    if (h == 0) {
      if (qf == 0) {
#pragma unroll
        for (int j = 0; j < 2; ++j) {
          float lt = lsum[j] + Sl[qg * 128 + l * 2 + j];
          lt += __shfl_xor(lt, 16);
          lt += __shfl_xor(lt, 32);
          lv[j] = 1.0f / lt;
        }
      }
      int q = q0 + qf * 16 + c;
      short* dst = ab + (size_t)(b * Sc + q) * Dc + hh * 64 + g * 4;
#pragma unroll
      for (int ohf = 0; ohf < 4; ++ohf) {
        f32x4 om = o[qf][ohf] +
            *(const f32x4*)(lds + qg * 4096 + ((l * 64 + ohf * 16) ^ ((l & 7) << 4)));
        s16x4 pk4;
#pragma unroll
        for (int r = 0; r < 4; ++r) pk4[r] = f2b(om[r] * lv[qf]);
        *(s16x4*)(dst + ohf * 16) = pk4;
      }
    }
    __syncthreads();
  }
}

// ---------------- launch ----------------
extern "C" void kernel_launch(void* const* d_in, const int* in_sizes, int n_in,
                              void* d_out, int out_size, void* d_ws, size_t ws_size,
                              hipStream_t stream) {
  const float* x  = (const float*)d_in[0];
  const float* Wq = (const float*)d_in[1];
  const float* Wk = (const float*)d_in[2];
  const float* Wv = (const float*)d_in[3];
  const float* Wo = (const float*)d_in[4];
  const float* bo = (const float*)d_in[5];
  float* out = (float*)d_out;

  char* p = (char*)d_ws;
  short* xb    = (short*)p; p += (size_t)Mc * Dc * 2;   // 8 MB
  short* wqb   = (short*)p; p += (size_t)Dc * Dc * 2;   // 2 MB
  short* wkb   = (short*)p; p += (size_t)Dc * Dc * 2;
  short* wvb   = (short*)p; p += (size_t)Dc * Dc * 2;
  short* wob   = (short*)p; p += (size_t)Dc * Dc * 2;
  short* Qb    = (short*)p; p += (size_t)Mc * Dc * 2;   // [B,H,S,HD], Q pre-scaled
  short* Kb    = (short*)p; p += (size_t)Mc * Dc * 2;   // [B,H,S,HD]
  short* Vtg   = (short*)p; p += (size_t)Mc * Dc * 2;   // [B,H,HD,S] (written by qkv)
  short* attnb = (short*)p; p += (size_t)Mc * Dc * 2;

  cvt_all<<<8192, 256, 0, stream>>>(x, Wq, Wk, Wv, Wo, xb, wqb, wkb, wvb, wob);
  qkv_kernel<<<dim3(Mc / 256, 12), 512, 0, stream>>>(xb, wqb, wkb, wvb, Qb, Kb, Vtg);
  attn_kernel<<<dim3(Bc * Hc, Sc / 128), 512, 0, stream>>>(Qb, Kb, Vtg, attnb);
  oproj_kernel<<<dim3(Mc / 128, Dc / 128), 256, 0, stream>>>(attnb, wob, bo, out);
}